// Round 10
// baseline (497.109 us; speedup 1.0000x reference)
//
#include <hip/hip_runtime.h>
#include <hip/hip_bf16.h>

#define B_ 8192
#define L_ 200

typedef __attribute__((ext_vector_type(4))) short s4v;
typedef __attribute__((ext_vector_type(8))) short s8v;
typedef __attribute__((ext_vector_type(16))) float f32x16;

__device__ __forceinline__ short f2bf(float f) {
    union { float f; unsigned u; } v; v.f = f;
    unsigned r = (v.u + 0x7fffu + ((v.u >> 16) & 1u)) >> 16;
    return (short)r;
}
__device__ __forceinline__ float bf2f(short s) {
    union { unsigned u; float f; } v; v.u = ((unsigned)(unsigned short)s) << 16;
    return v.f;
}
__device__ __forceinline__ unsigned cvtpk(float a, float b) {
    unsigned r;
    asm("v_cvt_pk_bf16_f32 %0, %1, %2" : "=v"(r) : "v"(a), "v"(b));
    return r;
}

// ---------------- ws layout (float units) ----------------
#define OFF_NETBF 0                          // B*128 bf16 = B*64 f
#define OFF_X     (OFF_NETBF + B_*64)        // B*512 bf16 (allocated as f32-sized region, used as shorts)
#define OFF_D0    (OFF_X + B_*512)           // B*512 bf16
#define OFF_D1    (OFF_D0 + B_*256)          // B*256 bf16
#define OFF_D2    (OFF_D1 + B_*128)          // B*128 bf16
#define OFF_ACC   (OFF_D2 + B_*64)           // 12*512
#define OFF_NORM  (OFF_ACC + 12*512)         // 1
#define OFF_PREP  (OFF_NORM + 1)             // 4096
#define OFF_W0T   (OFF_PREP + 4096)          // 512*128 bf16
#define OFF_W1T   (OFF_W0T + 32768)          // 256*512 bf16
#define OFF_W2T   (OFF_W1T + 65536)          // 128*256 bf16
#define OFF_FB1   (OFF_W2T + 16384)          // 256 f32
#define OFF_FB2   (OFF_FB1 + 256)            // 128 f32

// ---------------- one-time prep: attn frags (blk 0) + W0T (blk 1..32) + init (blk 33) ----------------
__global__ __launch_bounds__(256) void prep_w(
    const float* __restrict__ aW1, const float* __restrict__ aW2,
    const float* __restrict__ W0, float* __restrict__ wsP, short* __restrict__ W0T,
    float* __restrict__ acc, float* __restrict__ fb)
{
    const int t = threadIdx.x;
    if (blockIdx.x == 0) {
        short* W1BC = (short*)wsP;           // 1024 shorts
        short* W1D  = (short*)(wsP + 512);   // 1024 shorts
        float* W1AC = wsP + 1024;            // 1024 f32
        short* W2F  = (short*)(wsP + 2048);  // 2048 shorts
        for (int idx = t; idx < 1024; idx += 256) {
            int r = idx & 7, l = (idx >> 3) & 63, mt = idx >> 9;
            int i = ((l >> 5) << 3) + r, j = mt * 32 + (l & 31);
            W1BC[idx] = f2bf(aW1[(16 + i) * 64 + j] - aW1[(32 + i) * 64 + j]);
            W1D[idx]  = f2bf(aW1[(48 + i) * 64 + j]);
        }
        for (int idx = t; idx < 1024; idx += 256) {
            int i = idx & 15, j = idx >> 4;
            W1AC[idx] = aW1[i * 64 + j] + aW1[(32 + i) * 64 + j];
        }
        for (int idx = t; idx < 2048; idx += 256) {
            int r = idx & 7, l = (idx >> 3) & 63, ks = idx >> 9;
            int j2 = ks * 16 + ((l >> 5) << 3) + r, n2 = l & 31;
            W2F[idx] = f2bf(aW2[j2 * 32 + n2]);
        }
    } else if (blockIdx.x == 33) {
        for (int i = t; i < 12 * 512 + 1; i += 256) acc[i] = 0.f;
        if (t < 256 + 128) fb[t] = 0.f;
    } else {
        for (int idx = (blockIdx.x - 1) * 256 + t; idx < 512 * 128; idx += 32 * 256) {
            int n = idx & 511, k = idx >> 9;
            W0T[n * 128 + k] = (k < 82) ? f2bf(W0[k * 512 + n]) : (short)0;
        }
    }
}

// ---------------- per-layer fold prep (parallel tiled transpose + reduce) ----------------
__global__ __launch_bounds__(256) void prep_fold(
    const float* __restrict__ W, const float* __restrict__ bias,
    const float* __restrict__ sD, const float* __restrict__ qD,
    const float* __restrict__ g, const float* __restrict__ be,
    float invB, int K, int N,
    short* __restrict__ WT, float* __restrict__ fb)
{
    __shared__ short tile[64][65];
    __shared__ float sclS[64], sftS[64];
    __shared__ float red[256];
    const int t = threadIdx.x;
    const int bn = blockIdx.x * 64, bk = blockIdx.y * 64;

    if (t < 64) {
        const int k = bk + t;
        float m = sD[k] * invB;
        float v = fmaf(-m, m, qD[k] * invB);
        float sc = g[k] * rsqrtf(v + 1e-5f);
        sclS[t] = sc;
        sftS[t] = be[k] - m * sc;
    }
    __syncthreads();

    const int nn = t & 63, kk0 = (t >> 6) * 16;
    float part = 0.f;
    #pragma unroll
    for (int i = 0; i < 16; ++i) {
        const int kk = kk0 + i;
        float w = W[(size_t)(bk + kk) * N + bn + nn];
        tile[kk][nn] = f2bf(sclS[kk] * w);
        part = fmaf(sftS[kk], w, part);
    }
    red[t] = part;
    __syncthreads();

    {
        const int n = t >> 2, kp = (t & 3) * 16;
        short* dst = &WT[(size_t)(bn + n) * K + bk + kp];
        #pragma unroll
        for (int i = 0; i < 16; ++i) dst[i] = tile[kp + i][n];
    }
    if (t < 64) {
        float s = red[t] + red[t + 64] + red[t + 128] + red[t + 192];
        if (blockIdx.y == 0) s += bias[bn + t];
        atomicAdd(&fb[bn + t], s);
    }
}

// ---------------- MFMA attention + fused net-row build + l2 norm ----------------
__global__ __launch_bounds__(256) void attn_k(
    const int* __restrict__ feedid, const int* __restrict__ seq_ids,
    const int* __restrict__ seq_len,
    const float* __restrict__ e_feed, const float* __restrict__ e_seq,
    const float* __restrict__ ab1, const float* __restrict__ ab2,
    const float* __restrict__ ab3, const float* __restrict__ aW3,
    const float* __restrict__ wsP,
    const float* __restrict__ dense,
    const int* __restrict__ userid, const int* __restrict__ device_,
    const int* __restrict__ authorid, const int* __restrict__ song,
    const int* __restrict__ singer, const int* __restrict__ tag,
    const float* __restrict__ e_user, const float* __restrict__ e_dev,
    const float* __restrict__ e_auth, const float* __restrict__ e_song,
    const float* __restrict__ e_singer, const float* __restrict__ e_tag,
    short* __restrict__ nbf, float* __restrict__ norm_acc)
{
    __shared__ short KL[224 * 20];   // K bf16, row stride 20 shorts
    __shared__ short KQ[224 * 20];   // (K ∘ q) bf16
    __shared__ int   sidS[224];
    __shared__ float qS[16];
    __shared__ float qtS[64];
    __shared__ float w3S[32], ab2S[32];
    __shared__ float wS[224];
    __shared__ float pS[16 * 16];
    __shared__ float nrS[88];        // net row f32 (82 used)

    const short* W1BC = (const short*)wsP;
    const short* W1D  = (const short*)(wsP + 512);
    const float* W1AC = wsP + 1024;
    const short* W2F  = (const short*)(wsP + 2048);

    const int b = blockIdx.x, t = threadIdx.x;

    // prologue: all gathers issued up front (net-row segments overlap K-gather latency)
    if (t < 16) { float q = e_feed[(size_t)feedid[b] * 16 + t]; qS[t] = q; nrS[50 + t] = q; }
    if (t >= 32 && t < 64) w3S[t - 32] = aW3[t - 32];
    if (t >= 64 && t < 96) ab2S[t - 64] = ab2[t - 64];
    if (t >= 96 && t < 112) nrS[t - 96] = dense[(size_t)b * 16 + (t - 96)];
    if (t >= 112 && t < 128) nrS[16 + (t - 112)] = e_user[(size_t)userid[b] * 16 + (t - 112)];
    if (t >= 128 && t < 130) nrS[32 + (t - 128)] = e_dev[(size_t)device_[b] * 2 + (t - 128)];
    if (t >= 130 && t < 134) nrS[34 + (t - 130)] = e_auth[(size_t)authorid[b] * 4 + (t - 130)];
    if (t >= 134 && t < 138) nrS[38 + (t - 134)] = e_song[(size_t)song[b] * 4 + (t - 134)];
    if (t >= 138 && t < 142) nrS[42 + (t - 138)] = e_singer[(size_t)singer[b] * 4 + (t - 138)];
    if (t >= 142 && t < 146) nrS[46 + (t - 142)] = e_tag[(size_t)tag[b] * 4 + (t - 142)];
    if (t < 200) sidS[t] = seq_ids[(size_t)b * L_ + t];
    __syncthreads();

    // gather K rows: stage K and K∘q (f32 -> packed bf16 via cvt_pk)
    for (int idx = t; idx < 800; idx += 256) {
        int row = idx >> 2, p = idx & 3, c0 = p * 4;
        int sid = sidS[row];
        const float4 f4 = ((const float4*)(e_seq + (size_t)sid * 16))[p];
        uint2 kk, kq;
        kk.x = cvtpk(f4.x, f4.y);
        kk.y = cvtpk(f4.z, f4.w);
        kq.x = cvtpk(f4.x * qS[c0],     f4.y * qS[c0 + 1]);
        kq.y = cvtpk(f4.z * qS[c0 + 2], f4.w * qS[c0 + 3]);
        *(uint2*)&KL[row * 20 + c0] = kk;
        *(uint2*)&KQ[row * 20 + c0] = kq;
    }
    if (t < 96) {
        int row = 200 + (t >> 2), c0 = (t & 3) * 4;
        uint2 z = {0u, 0u};
        *(uint2*)&KL[row * 20 + c0] = z;
        *(uint2*)&KQ[row * 20 + c0] = z;
    }
    if (t < 64) {
        float s = ab1[t];
        #pragma unroll
        for (int i = 0; i < 16; ++i) s = fmaf(qS[i], W1AC[t * 16 + i], s);
        qtS[t] = s;
    }

    const int h = (t >> 5) & 1, l31 = t & 31, l63 = t & 63, wv = t >> 6;

    // static weight frags
    s8v w1bcF[2], w1dF[2], w2f[4];
    #pragma unroll
    for (int mt = 0; mt < 2; ++mt) {
        w1bcF[mt] = *(const s8v*)&W1BC[(mt * 64 + l63) * 8];
        w1dF[mt]  = *(const s8v*)&W1D[(mt * 64 + l63) * 8];
    }
    #pragma unroll
    for (int ks = 0; ks < 4; ++ks)
        w2f[ks] = *(const s8v*)&W2F[(ks * 64 + l63) * 8];

    __syncthreads();

    // hoist m-invariant LDS lookups into registers (static indices after unroll)
    float qtR0[16], qtR1[16], ab2R[16], w3R[16];
    #pragma unroll
    for (int r = 0; r < 16; ++r) {
        const int cr = (r & 3) + 8 * (r >> 2) + 4 * h;
        qtR0[r] = qtS[cr];
        qtR1[r] = qtS[32 + cr];
        ab2R[r] = ab2S[cr];
        w3R[r]  = w3S[cr];
    }

    union U8 { s8v s; unsigned u[4]; };
    const float ab3v = ab3[0];
    const int len = seq_len[b];

    for (int m = wv; m < 7; m += 4) {
        const int row = m * 32 + l31;
        s8v bK, bKQ;
        {
            s4v lo = *(const s4v*)&KL[row * 20 + h * 8];
            s4v hi = *(const s4v*)&KL[row * 20 + h * 8 + 4];
            bK[0] = lo[0]; bK[1] = lo[1]; bK[2] = lo[2]; bK[3] = lo[3];
            bK[4] = hi[0]; bK[5] = hi[1]; bK[6] = hi[2]; bK[7] = hi[3];
            s4v lo2 = *(const s4v*)&KQ[row * 20 + h * 8];
            s4v hi2 = *(const s4v*)&KQ[row * 20 + h * 8 + 4];
            bKQ[0] = lo2[0]; bKQ[1] = lo2[1]; bKQ[2] = lo2[2]; bKQ[3] = lo2[3];
            bKQ[4] = hi2[0]; bKQ[5] = hi2[1]; bKQ[6] = hi2[2]; bKQ[7] = hi2[3];
        }

        f32x16 c2;
        #pragma unroll
        for (int i = 0; i < 16; ++i) c2[i] = 0.f;

        #pragma unroll
        for (int mt = 0; mt < 2; ++mt) {
            f32x16 c;
            #pragma unroll
            for (int i = 0; i < 16; ++i) c[i] = 0.f;
            c = __builtin_amdgcn_mfma_f32_32x32x16_bf16(w1bcF[mt], bK,  c, 0, 0, 0);
            c = __builtin_amdgcn_mfma_f32_32x32x16_bf16(w1dF[mt],  bKQ, c, 0, 0, 0);

            unsigned pk[8], pks[8];
            #pragma unroll
            for (int i = 0; i < 8; ++i) {
                int r0 = 2 * i, r1 = r0 + 1;
                float q0 = mt ? qtR1[r0] : qtR0[r0];
                float q1 = mt ? qtR1[r1] : qtR0[r1];
                float v0 = fmaxf(c[r0] + q0, 0.f);
                float v1 = fmaxf(c[r1] + q1, 0.f);
                pk[i] = cvtpk(v0, v1);
                pks[i] = __shfl_xor(pk[i], 32);
            }
            {
                U8 bf2;
                bf2.u[0] = h ? pks[2] : pk[0];
                bf2.u[1] = h ? pks[3] : pk[1];
                bf2.u[2] = h ? pk[2]  : pks[0];
                bf2.u[3] = h ? pk[3]  : pks[1];
                c2 = __builtin_amdgcn_mfma_f32_32x32x16_bf16(w2f[mt * 2], bf2.s, c2, 0, 0, 0);
            }
            {
                U8 bf2;
                bf2.u[0] = h ? pks[6] : pk[4];
                bf2.u[1] = h ? pks[7] : pk[5];
                bf2.u[2] = h ? pk[6]  : pks[4];
                bf2.u[3] = h ? pk[7]  : pks[5];
                c2 = __builtin_amdgcn_mfma_f32_32x32x16_bf16(w2f[mt * 2 + 1], bf2.s, c2, 0, 0, 0);
            }
        }

        float part = 0.f;
        #pragma unroll
        for (int r = 0; r < 16; ++r)
            part = fmaf(fmaxf(c2[r] + ab2R[r], 0.f), w3R[r], part);
        float tot = part + __shfl_xor(part, 32) + ab3v;
        if (h == 0) wS[row] = (row < len) ? tot : 0.f;
    }
    __syncthreads();

    // att_out[c] = sum_l w[l]*K[l][c]
    {
        const int c = t & 15, ch = t >> 4, r0 = ch * 14;
        float s = 0.f;
        #pragma unroll
        for (int i = 0; i < 14; ++i)
            s = fmaf(wS[r0 + i], bf2f(KL[(r0 + i) * 20 + c]), s);
        pS[ch * 16 + c] = s;
    }
    __syncthreads();
    if (t < 16) {
        float s = 0.f;
        #pragma unroll
        for (int ch = 0; ch < 16; ++ch) s += pS[ch * 16 + t];
        nrS[66 + t] = s;
    }
    __syncthreads();

    // pack net row to bf16 (Kpad=128) + per-row l2 norm (wave 0 only)
    if (t < 64) {
        unsigned w = 0u;
        float sq = 0.f;
        if (t < 41) {
            float a = nrS[2 * t], c = nrS[2 * t + 1];
            w = cvtpk(a, c);
            if (t >= 8) sq = fmaf(a, a, c * c);
        }
        ((unsigned*)nbf)[(size_t)b * 64 + t] = w;
        sq += __shfl_xor(sq, 32); sq += __shfl_xor(sq, 16); sq += __shfl_xor(sq, 8);
        sq += __shfl_xor(sq, 4);  sq += __shfl_xor(sq, 2);  sq += __shfl_xor(sq, 1);
        if (t == 0) atomicAdd(norm_acc, sqrtf(sq));
    }
}

// ---------------- bf16 MFMA GEMM: 64x64 tile, 4 waves = 2x2 quadrants, BK=64, reg prefetch ----------------
// C output is bf16; column stats in f32.
__global__ __launch_bounds__(256) void gemm_mfma_stats(
    const short* __restrict__ A, int lda,
    const short* __restrict__ BT, int ldb,
    const float* __restrict__ bias,
    short* __restrict__ C, int N, int K,
    float* __restrict__ sout, float* __restrict__ qout)
{
    __shared__ short As[64 * 68];
    __shared__ short Bs[64 * 68];
    __shared__ float colS[64], colQ[64];

    const int bm = blockIdx.y * 64, bn = blockIdx.x * 64;
    const int t = threadIdx.x;
    const int wv = t >> 6, l31 = t & 31, h = (t >> 5) & 1;
    const int qr = wv >> 1, qc = wv & 1;

    if (t < 64) { colS[t] = 0.f; colQ[t] = 0.f; }

    const int row0 = t >> 3, part = (t & 7) * 8;
    s8v ar[2], br[2];
    #pragma unroll
    for (int i = 0; i < 2; ++i) {
        ar[i] = *(const s8v*)&A[(size_t)(bm + row0 + i * 32) * lda + part];
        br[i] = *(const s8v*)&BT[(size_t)(bn + row0 + i * 32) * ldb + part];
    }

    f32x16 acc;
    #pragma unroll
    for (int i = 0; i < 16; ++i) acc[i] = 0.f;

    const int nk = K >> 6;
    for (int kc = 0; kc < nk; ++kc) {
        #pragma unroll
        for (int i = 0; i < 2; ++i) {
            *(s8v*)&As[(row0 + i * 32) * 68 + part] = ar[i];
            *(s8v*)&Bs[(row0 + i * 32) * 68 + part] = br[i];
        }
        __syncthreads();
        if (kc + 1 < nk) {
            const int k0 = (kc + 1) << 6;
            #pragma unroll
            for (int i = 0; i < 2; ++i) {
                ar[i] = *(const s8v*)&A[(size_t)(bm + row0 + i * 32) * lda + k0 + part];
                br[i] = *(const s8v*)&BT[(size_t)(bn + row0 + i * 32) * ldb + k0 + part];
            }
        }
        #pragma unroll
        for (int ks = 0; ks < 4; ++ks) {
            const s8v af = *(const s8v*)&As[(qr * 32 + l31) * 68 + ks * 16 + h * 8];
            const s8v bf = *(const s8v*)&Bs[(qc * 32 + l31) * 68 + ks * 16 + h * 8];
            acc = __builtin_amdgcn_mfma_f32_32x32x16_bf16(af, bf, acc, 0, 0, 0);
        }
        __syncthreads();
    }

    const int col = bn + qc * 32 + l31;
    const float bv = bias[col];
    float s = 0.f, q = 0.f;
    #pragma unroll
    for (int r = 0; r < 16; ++r) {
        const int row = bm + qr * 32 + (r & 3) + 8 * (r >> 2) + 4 * h;
        float x = acc[r] + bv;
        C[(size_t)row * N + col] = f2bf(x);
        s += x; q = fmaf(x, x, q);
    }
    s += __shfl_xor(s, 32);
    q += __shfl_xor(q, 32);
    if (h == 0) {
        atomicAdd(&colS[qc * 32 + l31], s);
        atomicAdd(&colQ[qc * 32 + l31], q);
    }
    __syncthreads();
    if (t < 64) {
        atomicAdd(&sout[bn + t], colS[t]);
        atomicAdd(&qout[bn + t], colQ[t]);
    }
}

// ---------------- Dice elementwise (bf16 in, bf16 out) + D col stats ----------------
__global__ __launch_bounds__(256) void dice_stats(
    const short* __restrict__ X, short* __restrict__ D,
    const float* __restrict__ sin_, const float* __restrict__ qin_,
    const float* __restrict__ alpha,
    float* __restrict__ sout, float* __restrict__ qout,
    int N, float invB)
{
    __shared__ float cS[64], cQ[64];
    const int t = threadIdx.x;
    const int col = blockIdx.x * 64 + (t & 63);
    const int r0 = blockIdx.y * 64 + (t >> 6);
    if (t < 64) { cS[t] = 0.f; cQ[t] = 0.f; }
    __syncthreads();

    const float m = sin_[col] * invB;
    const float v = fmaf(-m, m, qin_[col] * invB);
    const float rs = rsqrtf(v + 1e-5f);
    const float al = alpha[col];

    float s = 0.f, q = 0.f;
    #pragma unroll
    for (int i = 0; i < 16; ++i) {
        const int r = r0 + i * 4;
        const float x = bf2f(X[(size_t)r * N + col]);
        const float xn = (x - m) * rs;
        const float p = 1.f / (1.f + __expf(-xn));
        const float d = x * (p + al * (1.f - p));
        D[(size_t)r * N + col] = f2bf(d);
        s += d; q = fmaf(d, d, q);
    }
    atomicAdd(&cS[t & 63], s);
    atomicAdd(&cQ[t & 63], q);
    __syncthreads();
    if (t < 64) {
        atomicAdd(&sout[blockIdx.x * 64 + t], cS[t]);
        atomicAdd(&qout[blockIdx.x * 64 + t], cQ[t]);
    }
}

// ---------------- final: BN-fold + logit, prob, l2 (bf16 Y) ----------------
__global__ __launch_bounds__(256) void final_k(
    const short* __restrict__ Y, const float* __restrict__ Wout,
    const float* __restrict__ bout, const float* __restrict__ norm_acc,
    const float* __restrict__ sD, const float* __restrict__ qD,
    const float* __restrict__ g, const float* __restrict__ be,
    float invB, float* __restrict__ out)
{
    const int wv = threadIdx.x >> 6, lane = threadIdx.x & 63;
    const int b = blockIdx.x * 4 + wv;
    const short* y = Y + (size_t)b * 128;

    float s = 0.f;
    #pragma unroll
    for (int hh = 0; hh < 2; ++hh) {
        const int c = hh * 64 + lane;
        const float m = sD[c] * invB;
        const float v = fmaf(-m, m, qD[c] * invB);
        const float yn = g[c] * (bf2f(y[c]) - m) * rsqrtf(v + 1e-5f) + be[c];
        s = fmaf(yn, Wout[c], s);
    }
    s += __shfl_xor(s, 32); s += __shfl_xor(s, 16);
    s += __shfl_xor(s, 8);  s += __shfl_xor(s, 4);
    s += __shfl_xor(s, 2);  s += __shfl_xor(s, 1);
    if (lane == 0) {
        float logit = s + bout[0];
        out[B_ + b] = logit;
        out[b] = 1.f / (1.f + __expf(-logit));
    }
    if (blockIdx.x == 0 && threadIdx.x == 0)
        out[2 * B_] = 0.2f * norm_acc[0] / (float)B_;
}

extern "C" void kernel_launch(void* const* d_in, const int* in_sizes, int n_in,
                              void* d_out, int out_size, void* d_ws, size_t ws_size,
                              hipStream_t stream)
{
    const float* dense    = (const float*)d_in[0];
    const int*   userid   = (const int*)d_in[1];
    const int*   device_  = (const int*)d_in[2];
    const int*   authorid = (const int*)d_in[3];
    const int*   song     = (const int*)d_in[4];
    const int*   singer   = (const int*)d_in[5];
    const int*   tag      = (const int*)d_in[6];
    const int*   feedid   = (const int*)d_in[7];
    const int*   seq_ids  = (const int*)d_in[8];
    const int*   seq_len  = (const int*)d_in[9];
    const float* e_user   = (const float*)d_in[10];
    const float* e_dev    = (const float*)d_in[11];
    const float* e_auth   = (const float*)d_in[12];
    const float* e_song   = (const float*)d_in[13];
    const float* e_singer = (const float*)d_in[14];
    const float* e_tag    = (const float*)d_in[15];
    const float* e_feed   = (const float*)d_in[16];
    const float* e_seq    = (const float*)d_in[17];
    const float* aW1 = (const float*)d_in[18];
    const float* ab1 = (const float*)d_in[19];
    const float* aW2 = (const float*)d_in[20];
    const float* ab2 = (const float*)d_in[21];
    const float* aW3 = (const float*)d_in[22];
    const float* ab3 = (const float*)d_in[23];
    const float* W0 = (const float*)d_in[24]; const float* b0 = (const float*)d_in[25];
    const float* al0 = (const float*)d_in[26]; const float* g0 = (const float*)d_in[27];
    const float* be0 = (const float*)d_in[28];
    const float* W1 = (const float*)d_in[29]; const float* b1 = (const float*)d_in[30];
    const float* al1 = (const float*)d_in[31]; const float* g1 = (const float*)d_in[32];
    const float* be1 = (const float*)d_in[33];
    const float* W2 = (const float*)d_in[34]; const float* b2 = (const float*)d_in[35];
    const float* al2 = (const float*)d_in[36]; const float* g2 = (const float*)d_in[37];
    const float* be2 = (const float*)d_in[38];
    const float* Wout = (const float*)d_in[39]; const float* bout = (const float*)d_in[40];

    float* ws    = (float*)d_ws;
    short* netbf = (short*)(ws + OFF_NETBF);
    short* Xbf   = (short*)(ws + OFF_X);
    short* d0    = (short*)(ws + OFF_D0);
    short* d1    = (short*)(ws + OFF_D1);
    short* d2    = (short*)(ws + OFF_D2);
    float* acc   = ws + OFF_ACC;
    float* norm  = ws + OFF_NORM;
    float* prep  = ws + OFF_PREP;
    short* W0T   = (short*)(ws + OFF_W0T);
    short* W1T   = (short*)(ws + OFF_W1T);
    short* W2T   = (short*)(ws + OFF_W2T);
    float* fb1   = ws + OFF_FB1;
    float* fb2   = ws + OFF_FB2;
    float* out   = (float*)d_out;

    float* sX0 = acc + 0*512;  float* qX0 = acc + 1*512;
    float* sD0 = acc + 2*512;  float* qD0 = acc + 3*512;
    float* sX1 = acc + 4*512;  float* qX1 = acc + 5*512;
    float* sD1 = acc + 6*512;  float* qD1 = acc + 7*512;
    float* sX2 = acc + 8*512;  float* qX2 = acc + 9*512;
    float* sD2 = acc + 10*512; float* qD2 = acc + 11*512;

    const float invB = 1.f / (float)B_;

    hipLaunchKernelGGL(prep_w, dim3(34), dim3(256), 0, stream,
                       aW1, aW2, W0, prep, W0T, acc, fb1);

    hipLaunchKernelGGL(attn_k, dim3(B_), dim3(256), 0, stream,
                       feedid, seq_ids, seq_len, e_feed, e_seq,
                       ab1, ab2, ab3, aW3, prep,
                       dense, userid, device_, authorid, song, singer, tag,
                       e_user, e_dev, e_auth, e_song, e_singer, e_tag,
                       netbf, norm);

    // layer 0: 82(pad128) -> 512
    hipLaunchKernelGGL(gemm_mfma_stats, dim3(512/64, B_/64), dim3(256), 0, stream,
                       netbf, 128, W0T, 128, b0, Xbf, 512, 128, sX0, qX0);
    hipLaunchKernelGGL(dice_stats, dim3(512/64, B_/64), dim3(256), 0, stream,
                       Xbf, d0, sX0, qX0, al0, sD0, qD0, 512, invB);
    hipLaunchKernelGGL(prep_fold, dim3(256/64, 512/64), dim3(256), 0, stream,
                       W1, b1, sD0, qD0, g0, be0, invB, 512, 256, W1T, fb1);

    // layer 1: 512 -> 256 (BN fold in W1T/fb1)
    hipLaunchKernelGGL(gemm_mfma_stats, dim3(256/64, B_/64), dim3(256), 0, stream,
                       d0, 512, W1T, 512, fb1, Xbf, 256, 512, sX1, qX1);
    hipLaunchKernelGGL(dice_stats, dim3(256/64, B_/64), dim3(256), 0, stream,
                       Xbf, d1, sX1, qX1, al1, sD1, qD1, 256, invB);
    hipLaunchKernelGGL(prep_fold, dim3(128/64, 256/64), dim3(256), 0, stream,
                       W2, b2, sD1, qD1, g1, be1, invB, 256, 128, W2T, fb2);

    // layer 2: 256 -> 128 (BN fold in W2T/fb2)
    hipLaunchKernelGGL(gemm_mfma_stats, dim3(128/64, B_/64), dim3(256), 0, stream,
                       d1, 256, W2T, 256, fb2, Xbf, 128, 256, sX2, qX2);
    hipLaunchKernelGGL(dice_stats, dim3(128/64, B_/64), dim3(256), 0, stream,
                       Xbf, d2, sX2, qX2, al2, sD2, qD2, 128, invB);

    // final: BN(D2) folded + output head
    hipLaunchKernelGGL(final_k, dim3(B_/4), dim3(256), 0, stream,
                       d2, Wout, bout, norm, sD2, qD2, g2, be2, invB, out);
}

// Round 11
// 280.877 us; speedup vs baseline: 1.7698x; 1.7698x over previous
//
#include <hip/hip_runtime.h>
#include <hip/hip_bf16.h>

#define B_ 8192
#define L_ 200

typedef __attribute__((ext_vector_type(4))) short s4v;
typedef __attribute__((ext_vector_type(8))) short s8v;
typedef __attribute__((ext_vector_type(16))) float f32x16;

__device__ __forceinline__ short f2bf(float f) {
    union { float f; unsigned u; } v; v.f = f;
    unsigned r = (v.u + 0x7fffu + ((v.u >> 16) & 1u)) >> 16;
    return (short)r;
}
__device__ __forceinline__ float bf2f(short s) {
    union { unsigned u; float f; } v; v.u = ((unsigned)(unsigned short)s) << 16;
    return v.f;
}
__device__ __forceinline__ unsigned cvtpk(float a, float b) {
    unsigned r;
    asm("v_cvt_pk_bf16_f32 %0, %1, %2" : "=v"(r) : "v"(a), "v"(b));
    return r;
}

// ---------------- ws layout (float units) ----------------
#define OFF_ATT   0                          // B*16 f32
#define OFF_NETBF (OFF_ATT + B_*16)          // B*128 bf16 = B*64 f
#define OFF_X     (OFF_NETBF + B_*64)        // B*512 bf16 (region sized as f32)
#define OFF_D0    (OFF_X + B_*512)           // B*512 bf16
#define OFF_D1    (OFF_D0 + B_*256)          // B*256 bf16
#define OFF_D2    (OFF_D1 + B_*128)          // B*128 bf16
#define OFF_ACC   (OFF_D2 + B_*64)           // 12*512
#define OFF_NORM  (OFF_ACC + 12*512)         // 1
#define OFF_PREP  (OFF_NORM + 1)             // 4096
#define OFF_W0T   (OFF_PREP + 4096)          // 512*128 bf16
#define OFF_W1T   (OFF_W0T + 32768)          // 256*512 bf16
#define OFF_W2T   (OFF_W1T + 65536)          // 128*256 bf16
#define OFF_FB1   (OFF_W2T + 16384)          // 256 f32
#define OFF_FB2   (OFF_FB1 + 256)            // 128 f32

// ---------------- one-time prep: attn frags (blk 0) + W0T (blk 1..32) + init (blk 33) ----------------
__global__ __launch_bounds__(256) void prep_w(
    const float* __restrict__ aW1, const float* __restrict__ aW2,
    const float* __restrict__ W0, float* __restrict__ wsP, short* __restrict__ W0T,
    float* __restrict__ acc, float* __restrict__ fb)
{
    const int t = threadIdx.x;
    if (blockIdx.x == 0) {
        short* W1BC = (short*)wsP;           // 1024 shorts
        short* W1D  = (short*)(wsP + 512);   // 1024 shorts
        float* W1AC = wsP + 1024;            // 1024 f32
        short* W2F  = (short*)(wsP + 2048);  // 2048 shorts
        for (int idx = t; idx < 1024; idx += 256) {
            int r = idx & 7, l = (idx >> 3) & 63, mt = idx >> 9;
            int i = ((l >> 5) << 3) + r, j = mt * 32 + (l & 31);
            W1BC[idx] = f2bf(aW1[(16 + i) * 64 + j] - aW1[(32 + i) * 64 + j]);
            W1D[idx]  = f2bf(aW1[(48 + i) * 64 + j]);
        }
        for (int idx = t; idx < 1024; idx += 256) {
            int i = idx & 15, j = idx >> 4;
            W1AC[idx] = aW1[i * 64 + j] + aW1[(32 + i) * 64 + j];
        }
        for (int idx = t; idx < 2048; idx += 256) {
            int r = idx & 7, l = (idx >> 3) & 63, ks = idx >> 9;
            int j2 = ks * 16 + ((l >> 5) << 3) + r, n2 = l & 31;
            W2F[idx] = f2bf(aW2[j2 * 32 + n2]);
        }
    } else if (blockIdx.x == 33) {
        for (int i = t; i < 12 * 512 + 1; i += 256) acc[i] = 0.f;
        if (t < 256 + 128) fb[t] = 0.f;
    } else {
        for (int idx = (blockIdx.x - 1) * 256 + t; idx < 512 * 128; idx += 32 * 256) {
            int n = idx & 511, k = idx >> 9;
            W0T[n * 128 + k] = (k < 82) ? f2bf(W0[k * 512 + n]) : (short)0;
        }
    }
}

// ---------------- per-layer fold prep (parallel tiled transpose + reduce) ----------------
__global__ __launch_bounds__(256) void prep_fold(
    const float* __restrict__ W, const float* __restrict__ bias,
    const float* __restrict__ sD, const float* __restrict__ qD,
    const float* __restrict__ g, const float* __restrict__ be,
    float invB, int K, int N,
    short* __restrict__ WT, float* __restrict__ fb)
{
    __shared__ short tile[64][65];
    __shared__ float sclS[64], sftS[64];
    __shared__ float red[256];
    const int t = threadIdx.x;
    const int bn = blockIdx.x * 64, bk = blockIdx.y * 64;

    if (t < 64) {
        const int k = bk + t;
        float m = sD[k] * invB;
        float v = fmaf(-m, m, qD[k] * invB);
        float sc = g[k] * rsqrtf(v + 1e-5f);
        sclS[t] = sc;
        sftS[t] = be[k] - m * sc;
    }
    __syncthreads();

    const int nn = t & 63, kk0 = (t >> 6) * 16;
    float part = 0.f;
    #pragma unroll
    for (int i = 0; i < 16; ++i) {
        const int kk = kk0 + i;
        float w = W[(size_t)(bk + kk) * N + bn + nn];
        tile[kk][nn] = f2bf(sclS[kk] * w);
        part = fmaf(sftS[kk], w, part);
    }
    red[t] = part;
    __syncthreads();

    {
        const int n = t >> 2, kp = (t & 3) * 16;
        short* dst = &WT[(size_t)(bn + n) * K + bk + kp];
        #pragma unroll
        for (int i = 0; i < 16; ++i) dst[i] = tile[kp + i][n];
    }
    if (t < 64) {
        float s = red[t] + red[t + 64] + red[t + 128] + red[t + 192];
        if (blockIdx.y == 0) s += bias[bn + t];
        atomicAdd(&fb[bn + t], s);
    }
}

// ---------------- MFMA attention (round-6 structure, measured 63 us) ----------------
__global__ __launch_bounds__(256) void attn_k(
    const int* __restrict__ feedid, const int* __restrict__ seq_ids,
    const int* __restrict__ seq_len,
    const float* __restrict__ e_feed, const float* __restrict__ e_seq,
    const float* __restrict__ ab1, const float* __restrict__ ab2,
    const float* __restrict__ ab3, const float* __restrict__ aW3,
    const float* __restrict__ wsP, float* __restrict__ att)
{
    __shared__ short KL[224 * 20];   // K bf16, row stride 20 shorts
    __shared__ short KQ[224 * 20];   // (K ∘ q) bf16
    __shared__ int   sidS[224];
    __shared__ float qS[16];
    __shared__ float qtS[64];
    __shared__ float w3S[32], ab2S[32];
    __shared__ float wS[224];
    __shared__ float pS[16 * 16];

    const short* W1BC = (const short*)wsP;
    const short* W1D  = (const short*)(wsP + 512);
    const float* W1AC = wsP + 1024;
    const short* W2F  = (const short*)(wsP + 2048);

    const int b = blockIdx.x, t = threadIdx.x;

    if (t < 16) qS[t] = e_feed[(size_t)feedid[b] * 16 + t];
    if (t >= 32 && t < 64) w3S[t - 32] = aW3[t - 32];
    if (t >= 64 && t < 96) ab2S[t - 64] = ab2[t - 64];
    if (t < 200) sidS[t] = seq_ids[(size_t)b * L_ + t];
    __syncthreads();

    // gather K rows: stage K and K∘q (f32 -> packed bf16 via cvt_pk)
    for (int idx = t; idx < 800; idx += 256) {
        int row = idx >> 2, p = idx & 3, c0 = p * 4;
        int sid = sidS[row];
        const float4 f4 = ((const float4*)(e_seq + (size_t)sid * 16))[p];
        uint2 kk, kq;
        kk.x = cvtpk(f4.x, f4.y);
        kk.y = cvtpk(f4.z, f4.w);
        kq.x = cvtpk(f4.x * qS[c0],     f4.y * qS[c0 + 1]);
        kq.y = cvtpk(f4.z * qS[c0 + 2], f4.w * qS[c0 + 3]);
        *(uint2*)&KL[row * 20 + c0] = kk;
        *(uint2*)&KQ[row * 20 + c0] = kq;
    }
    if (t < 96) {
        int row = 200 + (t >> 2), c0 = (t & 3) * 4;
        uint2 z = {0u, 0u};
        *(uint2*)&KL[row * 20 + c0] = z;
        *(uint2*)&KQ[row * 20 + c0] = z;
    }
    if (t < 64) {
        float s = ab1[t];
        #pragma unroll
        for (int i = 0; i < 16; ++i) s = fmaf(qS[i], W1AC[t * 16 + i], s);
        qtS[t] = s;
    }

    const int h = (t >> 5) & 1, l31 = t & 31, l63 = t & 63, wv = t >> 6;

    // static weight frags (L2-hot ws loads, once per block)
    s8v w1bcF[2], w1dF[2], w2f[4];
    #pragma unroll
    for (int mt = 0; mt < 2; ++mt) {
        w1bcF[mt] = *(const s8v*)&W1BC[(mt * 64 + l63) * 8];
        w1dF[mt]  = *(const s8v*)&W1D[(mt * 64 + l63) * 8];
    }
    #pragma unroll
    for (int ks = 0; ks < 4; ++ks)
        w2f[ks] = *(const s8v*)&W2F[(ks * 64 + l63) * 8];

    __syncthreads();

    union U8 { s8v s; unsigned u[4]; };
    const float ab3v = ab3[0];
    const int len = seq_len[b];

    for (int m = wv; m < 7; m += 4) {
        const int row = m * 32 + l31;
        s8v bK, bKQ;
        {
            s4v lo = *(const s4v*)&KL[row * 20 + h * 8];
            s4v hi = *(const s4v*)&KL[row * 20 + h * 8 + 4];
            bK[0] = lo[0]; bK[1] = lo[1]; bK[2] = lo[2]; bK[3] = lo[3];
            bK[4] = hi[0]; bK[5] = hi[1]; bK[6] = hi[2]; bK[7] = hi[3];
            s4v lo2 = *(const s4v*)&KQ[row * 20 + h * 8];
            s4v hi2 = *(const s4v*)&KQ[row * 20 + h * 8 + 4];
            bKQ[0] = lo2[0]; bKQ[1] = lo2[1]; bKQ[2] = lo2[2]; bKQ[3] = lo2[3];
            bKQ[4] = hi2[0]; bKQ[5] = hi2[1]; bKQ[6] = hi2[2]; bKQ[7] = hi2[3];
        }

        f32x16 c2;
        #pragma unroll
        for (int i = 0; i < 16; ++i) c2[i] = 0.f;

        #pragma unroll
        for (int mt = 0; mt < 2; ++mt) {
            f32x16 c;
            #pragma unroll
            for (int i = 0; i < 16; ++i) c[i] = 0.f;
            c = __builtin_amdgcn_mfma_f32_32x32x16_bf16(w1bcF[mt], bK,  c, 0, 0, 0);
            c = __builtin_amdgcn_mfma_f32_32x32x16_bf16(w1dF[mt],  bKQ, c, 0, 0, 0);

            // relu(c + qterm) -> packed bf16x2 (own half + swapped half); static indices
            unsigned pk[8], pks[8];
            #pragma unroll
            for (int i = 0; i < 8; ++i) {
                int r0 = 2 * i, r1 = r0 + 1;
                float v0 = fmaxf(c[r0] + qtS[mt * 32 + (r0 & 3) + 8 * (r0 >> 2) + 4 * h], 0.f);
                float v1 = fmaxf(c[r1] + qtS[mt * 32 + (r1 & 3) + 8 * (r1 >> 2) + 4 * h], 0.f);
                pk[i] = cvtpk(v0, v1);
                pks[i] = __shfl_xor(pk[i], 32);
            }
            {
                U8 bf2;
                bf2.u[0] = h ? pks[2] : pk[0];
                bf2.u[1] = h ? pks[3] : pk[1];
                bf2.u[2] = h ? pk[2]  : pks[0];
                bf2.u[3] = h ? pk[3]  : pks[1];
                c2 = __builtin_amdgcn_mfma_f32_32x32x16_bf16(w2f[mt * 2], bf2.s, c2, 0, 0, 0);
            }
            {
                U8 bf2;
                bf2.u[0] = h ? pks[6] : pk[4];
                bf2.u[1] = h ? pks[7] : pk[5];
                bf2.u[2] = h ? pk[6]  : pks[4];
                bf2.u[3] = h ? pk[7]  : pks[5];
                c2 = __builtin_amdgcn_mfma_f32_32x32x16_bf16(w2f[mt * 2 + 1], bf2.s, c2, 0, 0, 0);
            }
        }

        float part = 0.f;
        #pragma unroll
        for (int r = 0; r < 16; ++r) {
            int n2 = (r & 3) + 8 * (r >> 2) + 4 * h;
            part = fmaf(fmaxf(c2[r] + ab2S[n2], 0.f), w3S[n2], part);
        }
        float tot = part + __shfl_xor(part, 32) + ab3v;
        if (h == 0) wS[row] = (row < len) ? tot : 0.f;
    }
    __syncthreads();

    {
        const int c = t & 15, ch = t >> 4, r0 = ch * 14;
        float s = 0.f;
        #pragma unroll
        for (int i = 0; i < 14; ++i)
            s = fmaf(wS[r0 + i], bf2f(KL[(r0 + i) * 20 + c]), s);
        pS[ch * 16 + c] = s;
    }
    __syncthreads();
    if (t < 16) {
        float s = 0.f;
        #pragma unroll
        for (int ch = 0; ch < 16; ++ch) s += pS[ch * 16 + t];
        att[(size_t)b * 16 + t] = s;
    }
}

// ---------------- build net matrix (bf16, K padded to 128) + l2 norm ----------------
__global__ __launch_bounds__(256) void build_net(
    const float* __restrict__ dense,
    const int* __restrict__ userid, const int* __restrict__ device_,
    const int* __restrict__ authorid, const int* __restrict__ song,
    const int* __restrict__ singer, const int* __restrict__ tag,
    const int* __restrict__ feedid,
    const float* __restrict__ e_user, const float* __restrict__ e_dev,
    const float* __restrict__ e_auth, const float* __restrict__ e_song,
    const float* __restrict__ e_singer, const float* __restrict__ e_tag,
    const float* __restrict__ e_feed,
    const float* __restrict__ att, short* __restrict__ nbf,
    float* __restrict__ norm_acc)
{
    const int b = blockIdx.x * 256 + threadIdx.x;
    float row[82];
    const float* d = dense + (size_t)b * 16;
    #pragma unroll
    for (int i = 0; i < 16; ++i) row[i] = d[i];
    const float* eu = e_user + (size_t)userid[b] * 16;
    #pragma unroll
    for (int i = 0; i < 16; ++i) row[16 + i] = eu[i];
    const float* ed = e_dev + (size_t)device_[b] * 2;
    row[32] = ed[0]; row[33] = ed[1];
    const float* ea = e_auth + (size_t)authorid[b] * 4;
    #pragma unroll
    for (int i = 0; i < 4; ++i) row[34 + i] = ea[i];
    const float* es = e_song + (size_t)song[b] * 4;
    #pragma unroll
    for (int i = 0; i < 4; ++i) row[38 + i] = es[i];
    const float* eg = e_singer + (size_t)singer[b] * 4;
    #pragma unroll
    for (int i = 0; i < 4; ++i) row[42 + i] = eg[i];
    const float* et = e_tag + (size_t)tag[b] * 4;
    #pragma unroll
    for (int i = 0; i < 4; ++i) row[46 + i] = et[i];
    const float* ef = e_feed + (size_t)feedid[b] * 16;
    #pragma unroll
    for (int i = 0; i < 16; ++i) row[50 + i] = ef[i];
    const float* at = att + (size_t)b * 16;
    #pragma unroll
    for (int i = 0; i < 16; ++i) row[66 + i] = at[i];

    float sq = 0.f;
    #pragma unroll
    for (int i = 16; i < 82; ++i) sq = fmaf(row[i], row[i], sq);

    union { unsigned w[64]; uint4 w4[16]; } U;
    #pragma unroll
    for (int i = 0; i < 41; ++i) U.w[i] = cvtpk(row[2 * i], row[2 * i + 1]);
    #pragma unroll
    for (int i = 41; i < 64; ++i) U.w[i] = 0u;
    uint4* op = (uint4*)(nbf + (size_t)b * 128);
    #pragma unroll
    for (int c = 0; c < 16; ++c) op[c] = U.w4[c];

    float nrm = sqrtf(sq);
    nrm += __shfl_xor(nrm, 32); nrm += __shfl_xor(nrm, 16);
    nrm += __shfl_xor(nrm, 8);  nrm += __shfl_xor(nrm, 4);
    nrm += __shfl_xor(nrm, 2);  nrm += __shfl_xor(nrm, 1);
    if ((threadIdx.x & 63) == 0) atomicAdd(norm_acc, nrm);
}

// ---------------- bf16 MFMA GEMM: 64x64 tile, 4 waves = 2x2 quadrants, BK=64, reg prefetch ----------------
// C output is bf16; column stats in f32.
__global__ __launch_bounds__(256) void gemm_mfma_stats(
    const short* __restrict__ A, int lda,
    const short* __restrict__ BT, int ldb,
    const float* __restrict__ bias,
    short* __restrict__ C, int N, int K,
    float* __restrict__ sout, float* __restrict__ qout)
{
    __shared__ short As[64 * 68];
    __shared__ short Bs[64 * 68];
    __shared__ float colS[64], colQ[64];

    const int bm = blockIdx.y * 64, bn = blockIdx.x * 64;
    const int t = threadIdx.x;
    const int wv = t >> 6, l31 = t & 31, h = (t >> 5) & 1;
    const int qr = wv >> 1, qc = wv & 1;

    if (t < 64) { colS[t] = 0.f; colQ[t] = 0.f; }

    const int row0 = t >> 3, part = (t & 7) * 8;
    s8v ar[2], br[2];
    #pragma unroll
    for (int i = 0; i < 2; ++i) {
        ar[i] = *(const s8v*)&A[(size_t)(bm + row0 + i * 32) * lda + part];
        br[i] = *(const s8v*)&BT[(size_t)(bn + row0 + i * 32) * ldb + part];
    }

    f32x16 acc;
    #pragma unroll
    for (int i = 0; i < 16; ++i) acc[i] = 0.f;

    const int nk = K >> 6;
    for (int kc = 0; kc < nk; ++kc) {
        #pragma unroll
        for (int i = 0; i < 2; ++i) {
            *(s8v*)&As[(row0 + i * 32) * 68 + part] = ar[i];
            *(s8v*)&Bs[(row0 + i * 32) * 68 + part] = br[i];
        }
        __syncthreads();
        if (kc + 1 < nk) {
            const int k0 = (kc + 1) << 6;
            #pragma unroll
            for (int i = 0; i < 2; ++i) {
                ar[i] = *(const s8v*)&A[(size_t)(bm + row0 + i * 32) * lda + k0 + part];
                br[i] = *(const s8v*)&BT[(size_t)(bn + row0 + i * 32) * ldb + k0 + part];
            }
        }
        #pragma unroll
        for (int ks = 0; ks < 4; ++ks) {
            const s8v af = *(const s8v*)&As[(qr * 32 + l31) * 68 + ks * 16 + h * 8];
            const s8v bf = *(const s8v*)&Bs[(qc * 32 + l31) * 68 + ks * 16 + h * 8];
            acc = __builtin_amdgcn_mfma_f32_32x32x16_bf16(af, bf, acc, 0, 0, 0);
        }
        __syncthreads();
    }

    const int col = bn + qc * 32 + l31;
    const float bv = bias[col];
    float s = 0.f, q = 0.f;
    #pragma unroll
    for (int r = 0; r < 16; ++r) {
        const int row = bm + qr * 32 + (r & 3) + 8 * (r >> 2) + 4 * h;
        float x = acc[r] + bv;
        C[(size_t)row * N + col] = f2bf(x);
        s += x; q = fmaf(x, x, q);
    }
    s += __shfl_xor(s, 32);
    q += __shfl_xor(q, 32);
    if (h == 0) {
        atomicAdd(&colS[qc * 32 + l31], s);
        atomicAdd(&colQ[qc * 32 + l31], q);
    }
    __syncthreads();
    if (t < 64) {
        atomicAdd(&sout[bn + t], colS[t]);
        atomicAdd(&qout[bn + t], colQ[t]);
    }
}

// ---------------- Dice elementwise (bf16 in, bf16 out) + D col stats ----------------
__global__ __launch_bounds__(256) void dice_stats(
    const short* __restrict__ X, short* __restrict__ D,
    const float* __restrict__ sin_, const float* __restrict__ qin_,
    const float* __restrict__ alpha,
    float* __restrict__ sout, float* __restrict__ qout,
    int N, float invB)
{
    __shared__ float cS[64], cQ[64];
    const int t = threadIdx.x;
    const int col = blockIdx.x * 64 + (t & 63);
    const int r0 = blockIdx.y * 64 + (t >> 6);
    if (t < 64) { cS[t] = 0.f; cQ[t] = 0.f; }
    __syncthreads();

    const float m = sin_[col] * invB;
    const float v = fmaf(-m, m, qin_[col] * invB);
    const float rs = rsqrtf(v + 1e-5f);
    const float al = alpha[col];

    float s = 0.f, q = 0.f;
    #pragma unroll
    for (int i = 0; i < 16; ++i) {
        const int r = r0 + i * 4;
        const float x = bf2f(X[(size_t)r * N + col]);
        const float xn = (x - m) * rs;
        const float p = 1.f / (1.f + __expf(-xn));
        const float d = x * (p + al * (1.f - p));
        D[(size_t)r * N + col] = f2bf(d);
        s += d; q = fmaf(d, d, q);
    }
    atomicAdd(&cS[t & 63], s);
    atomicAdd(&cQ[t & 63], q);
    __syncthreads();
    if (t < 64) {
        atomicAdd(&sout[blockIdx.x * 64 + t], cS[t]);
        atomicAdd(&qout[blockIdx.x * 64 + t], cQ[t]);
    }
}

// ---------------- final: BN-fold + logit, prob, l2 (bf16 Y) ----------------
__global__ __launch_bounds__(256) void final_k(
    const short* __restrict__ Y, const float* __restrict__ Wout,
    const float* __restrict__ bout, const float* __restrict__ norm_acc,
    const float* __restrict__ sD, const float* __restrict__ qD,
    const float* __restrict__ g, const float* __restrict__ be,
    float invB, float* __restrict__ out)
{
    const int wv = threadIdx.x >> 6, lane = threadIdx.x & 63;
    const int b = blockIdx.x * 4 + wv;
    const short* y = Y + (size_t)b * 128;

    float s = 0.f;
    #pragma unroll
    for (int hh = 0; hh < 2; ++hh) {
        const int c = hh * 64 + lane;
        const float m = sD[c] * invB;
        const float v = fmaf(-m, m, qD[c] * invB);
        const float yn = g[c] * (bf2f(y[c]) - m) * rsqrtf(v + 1e-5f) + be[c];
        s = fmaf(yn, Wout[c], s);
    }
    s += __shfl_xor(s, 32); s += __shfl_xor(s, 16);
    s += __shfl_xor(s, 8);  s += __shfl_xor(s, 4);
    s += __shfl_xor(s, 2);  s += __shfl_xor(s, 1);
    if (lane == 0) {
        float logit = s + bout[0];
        out[B_ + b] = logit;
        out[b] = 1.f / (1.f + __expf(-logit));
    }
    if (blockIdx.x == 0 && threadIdx.x == 0)
        out[2 * B_] = 0.2f * norm_acc[0] / (float)B_;
}

extern "C" void kernel_launch(void* const* d_in, const int* in_sizes, int n_in,
                              void* d_out, int out_size, void* d_ws, size_t ws_size,
                              hipStream_t stream)
{
    const float* dense    = (const float*)d_in[0];
    const int*   userid   = (const int*)d_in[1];
    const int*   device_  = (const int*)d_in[2];
    const int*   authorid = (const int*)d_in[3];
    const int*   song     = (const int*)d_in[4];
    const int*   singer   = (const int*)d_in[5];
    const int*   tag      = (const int*)d_in[6];
    const int*   feedid   = (const int*)d_in[7];
    const int*   seq_ids  = (const int*)d_in[8];
    const int*   seq_len  = (const int*)d_in[9];
    const float* e_user   = (const float*)d_in[10];
    const float* e_dev    = (const float*)d_in[11];
    const float* e_auth   = (const float*)d_in[12];
    const float* e_song   = (const float*)d_in[13];
    const float* e_singer = (const float*)d_in[14];
    const float* e_tag    = (const float*)d_in[15];
    const float* e_feed   = (const float*)d_in[16];
    const float* e_seq    = (const float*)d_in[17];
    const float* aW1 = (const float*)d_in[18];
    const float* ab1 = (const float*)d_in[19];
    const float* aW2 = (const float*)d_in[20];
    const float* ab2 = (const float*)d_in[21];
    const float* aW3 = (const float*)d_in[22];
    const float* ab3 = (const float*)d_in[23];
    const float* W0 = (const float*)d_in[24]; const float* b0 = (const float*)d_in[25];
    const float* al0 = (const float*)d_in[26]; const float* g0 = (const float*)d_in[27];
    const float* be0 = (const float*)d_in[28];
    const float* W1 = (const float*)d_in[29]; const float* b1 = (const float*)d_in[30];
    const float* al1 = (const float*)d_in[31]; const float* g1 = (const float*)d_in[32];
    const float* be1 = (const float*)d_in[33];
    const float* W2 = (const float*)d_in[34]; const float* b2 = (const float*)d_in[35];
    const float* al2 = (const float*)d_in[36]; const float* g2 = (const float*)d_in[37];
    const float* be2 = (const float*)d_in[38];
    const float* Wout = (const float*)d_in[39]; const float* bout = (const float*)d_in[40];

    float* ws    = (float*)d_ws;
    float* att   = ws + OFF_ATT;
    short* netbf = (short*)(ws + OFF_NETBF);
    short* Xbf   = (short*)(ws + OFF_X);
    short* d0    = (short*)(ws + OFF_D0);
    short* d1    = (short*)(ws + OFF_D1);
    short* d2    = (short*)(ws + OFF_D2);
    float* acc   = ws + OFF_ACC;
    float* norm  = ws + OFF_NORM;
    float* prep  = ws + OFF_PREP;
    short* W0T   = (short*)(ws + OFF_W0T);
    short* W1T   = (short*)(ws + OFF_W1T);
    short* W2T   = (short*)(ws + OFF_W2T);
    float* fb1   = ws + OFF_FB1;
    float* fb2   = ws + OFF_FB2;
    float* out   = (float*)d_out;

    float* sX0 = acc + 0*512;  float* qX0 = acc + 1*512;
    float* sD0 = acc + 2*512;  float* qD0 = acc + 3*512;
    float* sX1 = acc + 4*512;  float* qX1 = acc + 5*512;
    float* sD1 = acc + 6*512;  float* qD1 = acc + 7*512;
    float* sX2 = acc + 8*512;  float* qX2 = acc + 9*512;
    float* sD2 = acc + 10*512; float* qD2 = acc + 11*512;

    const float invB = 1.f / (float)B_;

    hipLaunchKernelGGL(prep_w, dim3(34), dim3(256), 0, stream,
                       aW1, aW2, W0, prep, W0T, acc, fb1);

    hipLaunchKernelGGL(attn_k, dim3(B_), dim3(256), 0, stream,
                       feedid, seq_ids, seq_len, e_feed, e_seq,
                       ab1, ab2, ab3, aW3, prep, att);

    hipLaunchKernelGGL(build_net, dim3(B_/256), dim3(256), 0, stream,
                       dense, userid, device_, authorid, song, singer, tag, feedid,
                       e_user, e_dev, e_auth, e_song, e_singer, e_tag, e_feed,
                       att, netbf, norm);

    // layer 0: 82(pad128) -> 512
    hipLaunchKernelGGL(gemm_mfma_stats, dim3(512/64, B_/64), dim3(256), 0, stream,
                       netbf, 128, W0T, 128, b0, Xbf, 512, 128, sX0, qX0);
    hipLaunchKernelGGL(dice_stats, dim3(512/64, B_/64), dim3(256), 0, stream,
                       Xbf, d0, sX0, qX0, al0, sD0, qD0, 512, invB);
    hipLaunchKernelGGL(prep_fold, dim3(256/64, 512/64), dim3(256), 0, stream,
                       W1, b1, sD0, qD0, g0, be0, invB, 512, 256, W1T, fb1);

    // layer 1: 512 -> 256 (BN fold in W1T/fb1)
    hipLaunchKernelGGL(gemm_mfma_stats, dim3(256/64, B_/64), dim3(256), 0, stream,
                       d0, 512, W1T, 512, fb1, Xbf, 256, 512, sX1, qX1);
    hipLaunchKernelGGL(dice_stats, dim3(256/64, B_/64), dim3(256), 0, stream,
                       Xbf, d1, sX1, qX1, al1, sD1, qD1, 256, invB);
    hipLaunchKernelGGL(prep_fold, dim3(128/64, 256/64), dim3(256), 0, stream,
                       W2, b2, sD1, qD1, g1, be1, invB, 256, 128, W2T, fb2);

    // layer 2: 256 -> 128 (BN fold in W2T/fb2)
    hipLaunchKernelGGL(gemm_mfma_stats, dim3(128/64, B_/64), dim3(256), 0, stream,
                       d1, 256, W2T, 256, fb2, Xbf, 128, 256, sX2, qX2);
    hipLaunchKernelGGL(dice_stats, dim3(128/64, B_/64), dim3(256), 0, stream,
                       Xbf, d2, sX2, qX2, al2, sD2, qD2, 128, invB);

    // final: BN(D2) folded + output head
    hipLaunchKernelGGL(final_k, dim3(B_/4), dim3(256), 0, stream,
                       d2, Wout, bout, norm, sD2, qD2, g2, be2, invB, out);
}

// Round 12
// 273.595 us; speedup vs baseline: 1.8170x; 1.0266x over previous
//
#include <hip/hip_runtime.h>
#include <hip/hip_bf16.h>

#define B_ 8192
#define L_ 200
#define VF_ 100001

typedef __attribute__((ext_vector_type(4))) short s4v;
typedef __attribute__((ext_vector_type(8))) short s8v;
typedef __attribute__((ext_vector_type(16))) float f32x16;

__device__ __forceinline__ short f2bf(float f) {
    union { float f; unsigned u; } v; v.f = f;
    unsigned r = (v.u + 0x7fffu + ((v.u >> 16) & 1u)) >> 16;
    return (short)r;
}
__device__ __forceinline__ float bf2f(short s) {
    union { unsigned u; float f; } v; v.u = ((unsigned)(unsigned short)s) << 16;
    return v.f;
}
__device__ __forceinline__ unsigned cvtpk(float a, float b) {
    unsigned r;
    asm("v_cvt_pk_bf16_f32 %0, %1, %2" : "=v"(r) : "v"(a), "v"(b));
    return r;
}

// ---------------- ws layout (float units) ----------------
#define OFF_ATT   0                          // B*16 f32
#define OFF_NETBF (OFF_ATT + B_*16)          // B*128 bf16 = B*64 f
#define OFF_X     (OFF_NETBF + B_*64)        // B*512 bf16 (region sized as f32)
#define OFF_D0    (OFF_X + B_*512)           // B*512 bf16
#define OFF_D1    (OFF_D0 + B_*256)          // B*256 bf16
#define OFF_D2    (OFF_D1 + B_*128)          // B*128 bf16
#define OFF_ACC   (OFF_D2 + B_*64)           // 12*512
#define OFF_NORM  (OFF_ACC + 12*512)         // 1
#define OFF_PREP  (OFF_NORM + 1)             // 4096
#define OFF_W0T   (OFF_PREP + 4096)          // 512*128 bf16
#define OFF_W1T   (OFF_W0T + 32768)          // 256*512 bf16
#define OFF_W2T   (OFF_W1T + 65536)          // 128*256 bf16
#define OFF_FB1   (OFF_W2T + 16384)          // 256 f32
#define OFF_FB2   (OFF_FB1 + 256)            // 128 f32
#define OFF_ESEQB (OFF_FB2 + 128)            // VF_*16 bf16 = 800008 f

// ---------------- one-time prep: attn frags (blk 0) + W0T (blk 1..32) + init (blk 33)
// + e_seq f32->bf16 table (blk 34..97) ----------------
__global__ __launch_bounds__(256) void prep_w(
    const float* __restrict__ aW1, const float* __restrict__ aW2,
    const float* __restrict__ W0, const float* __restrict__ e_seq,
    float* __restrict__ wsP, short* __restrict__ W0T,
    float* __restrict__ acc, float* __restrict__ fb, short* __restrict__ esb)
{
    const int t = threadIdx.x;
    if (blockIdx.x == 0) {
        short* W1BC = (short*)wsP;           // 1024 shorts
        short* W1D  = (short*)(wsP + 512);   // 1024 shorts
        float* W1AC = wsP + 1024;            // 1024 f32
        short* W2F  = (short*)(wsP + 2048);  // 2048 shorts
        for (int idx = t; idx < 1024; idx += 256) {
            int r = idx & 7, l = (idx >> 3) & 63, mt = idx >> 9;
            int i = ((l >> 5) << 3) + r, j = mt * 32 + (l & 31);
            W1BC[idx] = f2bf(aW1[(16 + i) * 64 + j] - aW1[(32 + i) * 64 + j]);
            W1D[idx]  = f2bf(aW1[(48 + i) * 64 + j]);
        }
        for (int idx = t; idx < 1024; idx += 256) {
            int i = idx & 15, j = idx >> 4;
            W1AC[idx] = aW1[i * 64 + j] + aW1[(32 + i) * 64 + j];
        }
        for (int idx = t; idx < 2048; idx += 256) {
            int r = idx & 7, l = (idx >> 3) & 63, ks = idx >> 9;
            int j2 = ks * 16 + ((l >> 5) << 3) + r, n2 = l & 31;
            W2F[idx] = f2bf(aW2[j2 * 32 + n2]);
        }
    } else if (blockIdx.x == 33) {
        for (int i = t; i < 12 * 512 + 1; i += 256) acc[i] = 0.f;
        if (t < 256 + 128) fb[t] = 0.f;
    } else if (blockIdx.x < 33) {
        for (int idx = (blockIdx.x - 1) * 256 + t; idx < 512 * 128; idx += 32 * 256) {
            int n = idx & 511, k = idx >> 9;
            W0T[n * 128 + k] = (k < 82) ? f2bf(W0[k * 512 + n]) : (short)0;
        }
    } else {
        // e_seq f32 -> bf16 table: VF_*4 float4 chunks
        const int nch = VF_ * 4;
        for (int i = (blockIdx.x - 34) * 256 + t; i < nch; i += 64 * 256) {
            const float4 f = ((const float4*)e_seq)[i];
            uint2 o;
            o.x = cvtpk(f.x, f.y);
            o.y = cvtpk(f.z, f.w);
            ((uint2*)esb)[i] = o;
        }
    }
}

// ---------------- per-layer fold prep (parallel tiled transpose + reduce) ----------------
__global__ __launch_bounds__(256) void prep_fold(
    const float* __restrict__ W, const float* __restrict__ bias,
    const float* __restrict__ sD, const float* __restrict__ qD,
    const float* __restrict__ g, const float* __restrict__ be,
    float invB, int K, int N,
    short* __restrict__ WT, float* __restrict__ fb)
{
    __shared__ short tile[64][65];
    __shared__ float sclS[64], sftS[64];
    __shared__ float red[256];
    const int t = threadIdx.x;
    const int bn = blockIdx.x * 64, bk = blockIdx.y * 64;

    if (t < 64) {
        const int k = bk + t;
        float m = sD[k] * invB;
        float v = fmaf(-m, m, qD[k] * invB);
        float sc = g[k] * rsqrtf(v + 1e-5f);
        sclS[t] = sc;
        sftS[t] = be[k] - m * sc;
    }
    __syncthreads();

    const int nn = t & 63, kk0 = (t >> 6) * 16;
    float part = 0.f;
    #pragma unroll
    for (int i = 0; i < 16; ++i) {
        const int kk = kk0 + i;
        float w = W[(size_t)(bk + kk) * N + bn + nn];
        tile[kk][nn] = f2bf(sclS[kk] * w);
        part = fmaf(sftS[kk], w, part);
    }
    red[t] = part;
    __syncthreads();

    {
        const int n = t >> 2, kp = (t & 3) * 16;
        short* dst = &WT[(size_t)(bn + n) * K + bk + kp];
        #pragma unroll
        for (int i = 0; i < 16; ++i) dst[i] = tile[kp + i][n];
    }
    if (t < 64) {
        float s = red[t] + red[t + 64] + red[t + 128] + red[t + 192];
        if (blockIdx.y == 0) s += bias[bn + t];
        atomicAdd(&fb[bn + t], s);
    }
}

// ---------------- MFMA attention (round-6 structure; gather from bf16 table) ----------------
__global__ __launch_bounds__(256) void attn_k(
    const int* __restrict__ feedid, const int* __restrict__ seq_ids,
    const int* __restrict__ seq_len,
    const float* __restrict__ e_feed, const short* __restrict__ esb,
    const float* __restrict__ ab1, const float* __restrict__ ab2,
    const float* __restrict__ ab3, const float* __restrict__ aW3,
    const float* __restrict__ wsP, float* __restrict__ att)
{
    __shared__ short KL[224 * 20];   // K bf16, row stride 20 shorts
    __shared__ short KQ[224 * 20];   // (K ∘ q) bf16
    __shared__ int   sidS[224];
    __shared__ float qS[16];
    __shared__ float qtS[64];
    __shared__ float w3S[32], ab2S[32];
    __shared__ float wS[224];
    __shared__ float pS[16 * 16];

    const short* W1BC = (const short*)wsP;
    const short* W1D  = (const short*)(wsP + 512);
    const float* W1AC = wsP + 1024;
    const short* W2F  = (const short*)(wsP + 2048);

    const int b = blockIdx.x, t = threadIdx.x;

    if (t < 16) qS[t] = e_feed[(size_t)feedid[b] * 16 + t];
    if (t >= 32 && t < 64) w3S[t - 32] = aW3[t - 32];
    if (t >= 64 && t < 96) ab2S[t - 64] = ab2[t - 64];
    if (t < 200) sidS[t] = seq_ids[(size_t)b * L_ + t];
    __syncthreads();

    // gather K rows from bf16 table (8 B per lane-chunk); build K∘q
    for (int idx = t; idx < 800; idx += 256) {
        int row = idx >> 2, p = idx & 3, c0 = p * 4;
        int sid = sidS[row];
        s4v kv = *(const s4v*)&esb[(size_t)sid * 16 + c0];
        uint2 kq;
        kq.x = cvtpk(bf2f(kv[0]) * qS[c0],     bf2f(kv[1]) * qS[c0 + 1]);
        kq.y = cvtpk(bf2f(kv[2]) * qS[c0 + 2], bf2f(kv[3]) * qS[c0 + 3]);
        *(s4v*)&KL[row * 20 + c0] = kv;
        *(uint2*)&KQ[row * 20 + c0] = kq;
    }
    if (t < 96) {
        int row = 200 + (t >> 2), c0 = (t & 3) * 4;
        uint2 z = {0u, 0u};
        *(uint2*)&KL[row * 20 + c0] = z;
        *(uint2*)&KQ[row * 20 + c0] = z;
    }
    if (t < 64) {
        float s = ab1[t];
        #pragma unroll
        for (int i = 0; i < 16; ++i) s = fmaf(qS[i], W1AC[t * 16 + i], s);
        qtS[t] = s;
    }

    const int h = (t >> 5) & 1, l31 = t & 31, l63 = t & 63, wv = t >> 6;

    // static weight frags (L2-hot ws loads, once per block)
    s8v w1bcF[2], w1dF[2], w2f[4];
    #pragma unroll
    for (int mt = 0; mt < 2; ++mt) {
        w1bcF[mt] = *(const s8v*)&W1BC[(mt * 64 + l63) * 8];
        w1dF[mt]  = *(const s8v*)&W1D[(mt * 64 + l63) * 8];
    }
    #pragma unroll
    for (int ks = 0; ks < 4; ++ks)
        w2f[ks] = *(const s8v*)&W2F[(ks * 64 + l63) * 8];

    __syncthreads();

    union U8 { s8v s; unsigned u[4]; };
    const float ab3v = ab3[0];
    const int len = seq_len[b];

    for (int m = wv; m < 7; m += 4) {
        const int row = m * 32 + l31;
        s8v bK, bKQ;
        {
            s4v lo = *(const s4v*)&KL[row * 20 + h * 8];
            s4v hi = *(const s4v*)&KL[row * 20 + h * 8 + 4];
            bK[0] = lo[0]; bK[1] = lo[1]; bK[2] = lo[2]; bK[3] = lo[3];
            bK[4] = hi[0]; bK[5] = hi[1]; bK[6] = hi[2]; bK[7] = hi[3];
            s4v lo2 = *(const s4v*)&KQ[row * 20 + h * 8];
            s4v hi2 = *(const s4v*)&KQ[row * 20 + h * 8 + 4];
            bKQ[0] = lo2[0]; bKQ[1] = lo2[1]; bKQ[2] = lo2[2]; bKQ[3] = lo2[3];
            bKQ[4] = hi2[0]; bKQ[5] = hi2[1]; bKQ[6] = hi2[2]; bKQ[7] = hi2[3];
        }

        f32x16 c2;
        #pragma unroll
        for (int i = 0; i < 16; ++i) c2[i] = 0.f;

        #pragma unroll
        for (int mt = 0; mt < 2; ++mt) {
            f32x16 c;
            #pragma unroll
            for (int i = 0; i < 16; ++i) c[i] = 0.f;
            c = __builtin_amdgcn_mfma_f32_32x32x16_bf16(w1bcF[mt], bK,  c, 0, 0, 0);
            c = __builtin_amdgcn_mfma_f32_32x32x16_bf16(w1dF[mt],  bKQ, c, 0, 0, 0);

            // relu(c + qterm) -> packed bf16x2 (own half + swapped half); static indices
            unsigned pk[8], pks[8];
            #pragma unroll
            for (int i = 0; i < 8; ++i) {
                int r0 = 2 * i, r1 = r0 + 1;
                float v0 = fmaxf(c[r0] + qtS[mt * 32 + (r0 & 3) + 8 * (r0 >> 2) + 4 * h], 0.f);
                float v1 = fmaxf(c[r1] + qtS[mt * 32 + (r1 & 3) + 8 * (r1 >> 2) + 4 * h], 0.f);
                pk[i] = cvtpk(v0, v1);
                pks[i] = __shfl_xor(pk[i], 32);
            }
            {
                U8 bf2;
                bf2.u[0] = h ? pks[2] : pk[0];
                bf2.u[1] = h ? pks[3] : pk[1];
                bf2.u[2] = h ? pk[2]  : pks[0];
                bf2.u[3] = h ? pk[3]  : pks[1];
                c2 = __builtin_amdgcn_mfma_f32_32x32x16_bf16(w2f[mt * 2], bf2.s, c2, 0, 0, 0);
            }
            {
                U8 bf2;
                bf2.u[0] = h ? pks[6] : pk[4];
                bf2.u[1] = h ? pks[7] : pk[5];
                bf2.u[2] = h ? pk[6]  : pks[4];
                bf2.u[3] = h ? pk[7]  : pks[5];
                c2 = __builtin_amdgcn_mfma_f32_32x32x16_bf16(w2f[mt * 2 + 1], bf2.s, c2, 0, 0, 0);
            }
        }

        float part = 0.f;
        #pragma unroll
        for (int r = 0; r < 16; ++r) {
            int n2 = (r & 3) + 8 * (r >> 2) + 4 * h;
            part = fmaf(fmaxf(c2[r] + ab2S[n2], 0.f), w3S[n2], part);
        }
        float tot = part + __shfl_xor(part, 32) + ab3v;
        if (h == 0) wS[row] = (row < len) ? tot : 0.f;
    }
    __syncthreads();

    {
        const int c = t & 15, ch = t >> 4, r0 = ch * 14;
        float s = 0.f;
        #pragma unroll
        for (int i = 0; i < 14; ++i)
            s = fmaf(wS[r0 + i], bf2f(KL[(r0 + i) * 20 + c]), s);
        pS[ch * 16 + c] = s;
    }
    __syncthreads();
    if (t < 16) {
        float s = 0.f;
        #pragma unroll
        for (int ch = 0; ch < 16; ++ch) s += pS[ch * 16 + t];
        att[(size_t)b * 16 + t] = s;
    }
}

// ---------------- build net matrix (bf16, K padded to 128) + l2 norm ----------------
__global__ __launch_bounds__(256) void build_net(
    const float* __restrict__ dense,
    const int* __restrict__ userid, const int* __restrict__ device_,
    const int* __restrict__ authorid, const int* __restrict__ song,
    const int* __restrict__ singer, const int* __restrict__ tag,
    const int* __restrict__ feedid,
    const float* __restrict__ e_user, const float* __restrict__ e_dev,
    const float* __restrict__ e_auth, const float* __restrict__ e_song,
    const float* __restrict__ e_singer, const float* __restrict__ e_tag,
    const float* __restrict__ e_feed,
    const float* __restrict__ att, short* __restrict__ nbf,
    float* __restrict__ norm_acc)
{
    const int b = blockIdx.x * 256 + threadIdx.x;
    float row[82];
    const float* d = dense + (size_t)b * 16;
    #pragma unroll
    for (int i = 0; i < 16; ++i) row[i] = d[i];
    const float* eu = e_user + (size_t)userid[b] * 16;
    #pragma unroll
    for (int i = 0; i < 16; ++i) row[16 + i] = eu[i];
    const float* ed = e_dev + (size_t)device_[b] * 2;
    row[32] = ed[0]; row[33] = ed[1];
    const float* ea = e_auth + (size_t)authorid[b] * 4;
    #pragma unroll
    for (int i = 0; i < 4; ++i) row[34 + i] = ea[i];
    const float* es = e_song + (size_t)song[b] * 4;
    #pragma unroll
    for (int i = 0; i < 4; ++i) row[38 + i] = es[i];
    const float* eg = e_singer + (size_t)singer[b] * 4;
    #pragma unroll
    for (int i = 0; i < 4; ++i) row[42 + i] = eg[i];
    const float* et = e_tag + (size_t)tag[b] * 4;
    #pragma unroll
    for (int i = 0; i < 4; ++i) row[46 + i] = et[i];
    const float* ef = e_feed + (size_t)feedid[b] * 16;
    #pragma unroll
    for (int i = 0; i < 16; ++i) row[50 + i] = ef[i];
    const float* at = att + (size_t)b * 16;
    #pragma unroll
    for (int i = 0; i < 16; ++i) row[66 + i] = at[i];

    float sq = 0.f;
    #pragma unroll
    for (int i = 16; i < 82; ++i) sq = fmaf(row[i], row[i], sq);

    union { unsigned w[64]; uint4 w4[16]; } U;
    #pragma unroll
    for (int i = 0; i < 41; ++i) U.w[i] = cvtpk(row[2 * i], row[2 * i + 1]);
    #pragma unroll
    for (int i = 41; i < 64; ++i) U.w[i] = 0u;
    uint4* op = (uint4*)(nbf + (size_t)b * 128);
    #pragma unroll
    for (int c = 0; c < 16; ++c) op[c] = U.w4[c];

    float nrm = sqrtf(sq);
    nrm += __shfl_xor(nrm, 32); nrm += __shfl_xor(nrm, 16);
    nrm += __shfl_xor(nrm, 8);  nrm += __shfl_xor(nrm, 4);
    nrm += __shfl_xor(nrm, 2);  nrm += __shfl_xor(nrm, 1);
    if ((threadIdx.x & 63) == 0) atomicAdd(norm_acc, nrm);
}

// ---------------- bf16 MFMA GEMM: 64x64 tile, 4 waves = 2x2 quadrants, BK=64, reg prefetch ----------------
// C output is bf16; column stats in f32.
__global__ __launch_bounds__(256) void gemm_mfma_stats(
    const short* __restrict__ A, int lda,
    const short* __restrict__ BT, int ldb,
    const float* __restrict__ bias,
    short* __restrict__ C, int N, int K,
    float* __restrict__ sout, float* __restrict__ qout)
{
    __shared__ short As[64 * 68];
    __shared__ short Bs[64 * 68];
    __shared__ float colS[64], colQ[64];

    const int bm = blockIdx.y * 64, bn = blockIdx.x * 64;
    const int t = threadIdx.x;
    const int wv = t >> 6, l31 = t & 31, h = (t >> 5) & 1;
    const int qr = wv >> 1, qc = wv & 1;

    if (t < 64) { colS[t] = 0.f; colQ[t] = 0.f; }

    const int row0 = t >> 3, part = (t & 7) * 8;
    s8v ar[2], br[2];
    #pragma unroll
    for (int i = 0; i < 2; ++i) {
        ar[i] = *(const s8v*)&A[(size_t)(bm + row0 + i * 32) * lda + part];
        br[i] = *(const s8v*)&BT[(size_t)(bn + row0 + i * 32) * ldb + part];
    }

    f32x16 acc;
    #pragma unroll
    for (int i = 0; i < 16; ++i) acc[i] = 0.f;

    const int nk = K >> 6;
    for (int kc = 0; kc < nk; ++kc) {
        #pragma unroll
        for (int i = 0; i < 2; ++i) {
            *(s8v*)&As[(row0 + i * 32) * 68 + part] = ar[i];
            *(s8v*)&Bs[(row0 + i * 32) * 68 + part] = br[i];
        }
        __syncthreads();
        if (kc + 1 < nk) {
            const int k0 = (kc + 1) << 6;
            #pragma unroll
            for (int i = 0; i < 2; ++i) {
                ar[i] = *(const s8v*)&A[(size_t)(bm + row0 + i * 32) * lda + k0 + part];
                br[i] = *(const s8v*)&BT[(size_t)(bn + row0 + i * 32) * ldb + k0 + part];
            }
        }
        #pragma unroll
        for (int ks = 0; ks < 4; ++ks) {
            const s8v af = *(const s8v*)&As[(qr * 32 + l31) * 68 + ks * 16 + h * 8];
            const s8v bf = *(const s8v*)&Bs[(qc * 32 + l31) * 68 + ks * 16 + h * 8];
            acc = __builtin_amdgcn_mfma_f32_32x32x16_bf16(af, bf, acc, 0, 0, 0);
        }
        __syncthreads();
    }

    const int col = bn + qc * 32 + l31;
    const float bv = bias[col];
    float s = 0.f, q = 0.f;
    #pragma unroll
    for (int r = 0; r < 16; ++r) {
        const int row = bm + qr * 32 + (r & 3) + 8 * (r >> 2) + 4 * h;
        float x = acc[r] + bv;
        C[(size_t)row * N + col] = f2bf(x);
        s += x; q = fmaf(x, x, q);
    }
    s += __shfl_xor(s, 32);
    q += __shfl_xor(q, 32);
    if (h == 0) {
        atomicAdd(&colS[qc * 32 + l31], s);
        atomicAdd(&colQ[qc * 32 + l31], q);
    }
    __syncthreads();
    if (t < 64) {
        atomicAdd(&sout[bn + t], colS[t]);
        atomicAdd(&qout[bn + t], colQ[t]);
    }
}

// ---------------- Dice elementwise (bf16 in, bf16 out) + D col stats ----------------
__global__ __launch_bounds__(256) void dice_stats(
    const short* __restrict__ X, short* __restrict__ D,
    const float* __restrict__ sin_, const float* __restrict__ qin_,
    const float* __restrict__ alpha,
    float* __restrict__ sout, float* __restrict__ qout,
    int N, float invB)
{
    __shared__ float cS[64], cQ[64];
    const int t = threadIdx.x;
    const int col = blockIdx.x * 64 + (t & 63);
    const int r0 = blockIdx.y * 64 + (t >> 6);
    if (t < 64) { cS[t] = 0.f; cQ[t] = 0.f; }
    __syncthreads();

    const float m = sin_[col] * invB;
    const float v = fmaf(-m, m, qin_[col] * invB);
    const float rs = rsqrtf(v + 1e-5f);
    const float al = alpha[col];

    float s = 0.f, q = 0.f;
    #pragma unroll
    for (int i = 0; i < 16; ++i) {
        const int r = r0 + i * 4;
        const float x = bf2f(X[(size_t)r * N + col]);
        const float xn = (x - m) * rs;
        const float p = 1.f / (1.f + __expf(-xn));
        const float d = x * (p + al * (1.f - p));
        D[(size_t)r * N + col] = f2bf(d);
        s += d; q = fmaf(d, d, q);
    }
    atomicAdd(&cS[t & 63], s);
    atomicAdd(&cQ[t & 63], q);
    __syncthreads();
    if (t < 64) {
        atomicAdd(&sout[blockIdx.x * 64 + t], cS[t]);
        atomicAdd(&qout[blockIdx.x * 64 + t], cQ[t]);
    }
}

// ---------------- final: BN-fold + logit, prob, l2 (bf16 Y) ----------------
__global__ __launch_bounds__(256) void final_k(
    const short* __restrict__ Y, const float* __restrict__ Wout,
    const float* __restrict__ bout, const float* __restrict__ norm_acc,
    const float* __restrict__ sD, const float* __restrict__ qD,
    const float* __restrict__ g, const float* __restrict__ be,
    float invB, float* __restrict__ out)
{
    const int wv = threadIdx.x >> 6, lane = threadIdx.x & 63;
    const int b = blockIdx.x * 4 + wv;
    const short* y = Y + (size_t)b * 128;

    float s = 0.f;
    #pragma unroll
    for (int hh = 0; hh < 2; ++hh) {
        const int c = hh * 64 + lane;
        const float m = sD[c] * invB;
        const float v = fmaf(-m, m, qD[c] * invB);
        const float yn = g[c] * (bf2f(y[c]) - m) * rsqrtf(v + 1e-5f) + be[c];
        s = fmaf(yn, Wout[c], s);
    }
    s += __shfl_xor(s, 32); s += __shfl_xor(s, 16);
    s += __shfl_xor(s, 8);  s += __shfl_xor(s, 4);
    s += __shfl_xor(s, 2);  s += __shfl_xor(s, 1);
    if (lane == 0) {
        float logit = s + bout[0];
        out[B_ + b] = logit;
        out[b] = 1.f / (1.f + __expf(-logit));
    }
    if (blockIdx.x == 0 && threadIdx.x == 0)
        out[2 * B_] = 0.2f * norm_acc[0] / (float)B_;
}

extern "C" void kernel_launch(void* const* d_in, const int* in_sizes, int n_in,
                              void* d_out, int out_size, void* d_ws, size_t ws_size,
                              hipStream_t stream)
{
    const float* dense    = (const float*)d_in[0];
    const int*   userid   = (const int*)d_in[1];
    const int*   device_  = (const int*)d_in[2];
    const int*   authorid = (const int*)d_in[3];
    const int*   song     = (const int*)d_in[4];
    const int*   singer   = (const int*)d_in[5];
    const int*   tag      = (const int*)d_in[6];
    const int*   feedid   = (const int*)d_in[7];
    const int*   seq_ids  = (const int*)d_in[8];
    const int*   seq_len  = (const int*)d_in[9];
    const float* e_user   = (const float*)d_in[10];
    const float* e_dev    = (const float*)d_in[11];
    const float* e_auth   = (const float*)d_in[12];
    const float* e_song   = (const float*)d_in[13];
    const float* e_singer = (const float*)d_in[14];
    const float* e_tag    = (const float*)d_in[15];
    const float* e_feed   = (const float*)d_in[16];
    const float* e_seq    = (const float*)d_in[17];
    const float* aW1 = (const float*)d_in[18];
    const float* ab1 = (const float*)d_in[19];
    const float* aW2 = (const float*)d_in[20];
    const float* ab2 = (const float*)d_in[21];
    const float* aW3 = (const float*)d_in[22];
    const float* ab3 = (const float*)d_in[23];
    const float* W0 = (const float*)d_in[24]; const float* b0 = (const float*)d_in[25];
    const float* al0 = (const float*)d_in[26]; const float* g0 = (const float*)d_in[27];
    const float* be0 = (const float*)d_in[28];
    const float* W1 = (const float*)d_in[29]; const float* b1 = (const float*)d_in[30];
    const float* al1 = (const float*)d_in[31]; const float* g1 = (const float*)d_in[32];
    const float* be1 = (const float*)d_in[33];
    const float* W2 = (const float*)d_in[34]; const float* b2 = (const float*)d_in[35];
    const float* al2 = (const float*)d_in[36]; const float* g2 = (const float*)d_in[37];
    const float* be2 = (const float*)d_in[38];
    const float* Wout = (const float*)d_in[39]; const float* bout = (const float*)d_in[40];

    float* ws    = (float*)d_ws;
    float* att   = ws + OFF_ATT;
    short* netbf = (short*)(ws + OFF_NETBF);
    short* Xbf   = (short*)(ws + OFF_X);
    short* d0    = (short*)(ws + OFF_D0);
    short* d1    = (short*)(ws + OFF_D1);
    short* d2    = (short*)(ws + OFF_D2);
    float* acc   = ws + OFF_ACC;
    float* norm  = ws + OFF_NORM;
    float* prep  = ws + OFF_PREP;
    short* W0T   = (short*)(ws + OFF_W0T);
    short* W1T   = (short*)(ws + OFF_W1T);
    short* W2T   = (short*)(ws + OFF_W2T);
    float* fb1   = ws + OFF_FB1;
    float* fb2   = ws + OFF_FB2;
    short* esb   = (short*)(ws + OFF_ESEQB);
    float* out   = (float*)d_out;

    float* sX0 = acc + 0*512;  float* qX0 = acc + 1*512;
    float* sD0 = acc + 2*512;  float* qD0 = acc + 3*512;
    float* sX1 = acc + 4*512;  float* qX1 = acc + 5*512;
    float* sD1 = acc + 6*512;  float* qD1 = acc + 7*512;
    float* sX2 = acc + 8*512;  float* qX2 = acc + 9*512;
    float* sD2 = acc + 10*512; float* qD2 = acc + 11*512;

    const float invB = 1.f / (float)B_;

    hipLaunchKernelGGL(prep_w, dim3(98), dim3(256), 0, stream,
                       aW1, aW2, W0, e_seq, prep, W0T, acc, fb1, esb);

    hipLaunchKernelGGL(attn_k, dim3(B_), dim3(256), 0, stream,
                       feedid, seq_ids, seq_len, e_feed, esb,
                       ab1, ab2, ab3, aW3, prep, att);

    hipLaunchKernelGGL(build_net, dim3(B_/256), dim3(256), 0, stream,
                       dense, userid, device_, authorid, song, singer, tag, feedid,
                       e_user, e_dev, e_auth, e_song, e_singer, e_tag, e_feed,
                       att, netbf, norm);

    // layer 0: 82(pad128) -> 512
    hipLaunchKernelGGL(gemm_mfma_stats, dim3(512/64, B_/64), dim3(256), 0, stream,
                       netbf, 128, W0T, 128, b0, Xbf, 512, 128, sX0, qX0);
    hipLaunchKernelGGL(dice_stats, dim3(512/64, B_/64), dim3(256), 0, stream,
                       Xbf, d0, sX0, qX0, al0, sD0, qD0, 512, invB);
    hipLaunchKernelGGL(prep_fold, dim3(256/64, 512/64), dim3(256), 0, stream,
                       W1, b1, sD0, qD0, g0, be0, invB, 512, 256, W1T, fb1);

    // layer 1: 512 -> 256 (BN fold in W1T/fb1)
    hipLaunchKernelGGL(gemm_mfma_stats, dim3(256/64, B_/64), dim3(256), 0, stream,
                       d0, 512, W1T, 512, fb1, Xbf, 256, 512, sX1, qX1);
    hipLaunchKernelGGL(dice_stats, dim3(256/64, B_/64), dim3(256), 0, stream,
                       Xbf, d1, sX1, qX1, al1, sD1, qD1, 256, invB);
    hipLaunchKernelGGL(prep_fold, dim3(128/64, 256/64), dim3(256), 0, stream,
                       W2, b2, sD1, qD1, g1, be1, invB, 256, 128, W2T, fb2);

    // layer 2: 256 -> 128 (BN fold in W2T/fb2)
    hipLaunchKernelGGL(gemm_mfma_stats, dim3(128/64, B_/64), dim3(256), 0, stream,
                       d1, 256, W2T, 256, fb2, Xbf, 128, 256, sX2, qX2);
    hipLaunchKernelGGL(dice_stats, dim3(128/64, B_/64), dim3(256), 0, stream,
                       Xbf, d2, sX2, qX2, al2, sD2, qD2, 128, invB);

    // final: BN(D2) folded + output head
    hipLaunchKernelGGL(final_k, dim3(B_/4), dim3(256), 0, stream,
                       d2, Wout, bout, norm, sD2, qD2, g2, be2, invB, out);
}